// Round 9
// baseline (442.070 us; speedup 1.0000x reference)
//
#include <hip/hip_runtime.h>
#include <math.h>

#define D_NODE 100
#define D_HID  300
static const int TSEQ = 512, LQn = 256, NNODE = 256;

typedef unsigned int u32;
typedef unsigned short u16;
typedef __attribute__((ext_vector_type(8))) short bf16x8;   // 8 bf16 = 4 VGPRs
typedef __attribute__((ext_vector_type(4))) float f32x4;

__device__ __forceinline__ float bf2f(u16 v){ return __uint_as_float(((u32)v) << 16); }
__device__ __forceinline__ u16 f2bf(float f){
    u32 u = __float_as_uint(f);
    return (u16)((u + 0x7fffu + ((u >> 16) & 1u)) >> 16);
}
__device__ __forceinline__ u32 pack_bf(float lo, float hi){
    return ((u32)f2bf(lo)) | (((u32)f2bf(hi)) << 16);
}
__device__ __forceinline__ void gload_lds16(const void* g, void* l){
    __builtin_amdgcn_global_load_lds(
        (const __attribute__((address_space(1))) u32*)g,
        (__attribute__((address_space(3))) u32*)l, 16, 0, 0);
}
// fast sigmoid / tanh on v_exp_f32 + v_rcp_f32 (saturate correctly at +/-inf)
__device__ __forceinline__ float fsig(float x){
    return __builtin_amdgcn_rcpf(1.f + __expf(-x));
}
__device__ __forceinline__ float ftanh(float x){
    return 1.f - 2.f*__builtin_amdgcn_rcpf(1.f + __expf(2.f*x));
}

// ---------------- K0: fold W_mean into GRU weights -> W4bf bf16 [dir][gate][320 j][128 k] ----------------
__global__ __launch_bounds__(128)
void k0_prep(const float* __restrict__ Wm, const float* __restrict__ bm,
             const float* __restrict__ Wihf, const float* __restrict__ bihf, const float* __restrict__ bhhf,
             const float* __restrict__ Wihb, const float* __restrict__ bihb, const float* __restrict__ bhhb,
             u16* __restrict__ W4bf, float* __restrict__ bc, float* __restrict__ bhhn)
{
    int j = blockIdx.x, g = blockIdx.y, dir = blockIdx.z;
    int tid = threadIdx.x;
    u16* wout = W4bf + ((size_t)((dir*3+g)*320 + j))*128;
    if (j >= D_HID) {
        wout[tid] = 0;
        if (tid == 0) { bc[(dir*3+g)*320 + j] = 0.f; if (g==2) bhhn[dir*320+j] = 0.f; }
        return;
    }
    const float* Wih = dir ? Wihb : Wihf;
    const float* bih = dir ? bihb : bihf;
    const float* bhh = dir ? bhhb : bhhf;
    const float* wrow = Wih + (size_t)(g*D_HID + j)*D_HID;
    int k = tid;
    float s = 0.f;
    if (k < D_NODE)
        for (int q = 0; q < D_HID; ++q)
            s = fmaf(wrow[q], Wm[q*D_NODE + k], s);
    wout[k] = f2bf(k < D_NODE ? s : 0.f);

    __shared__ float red[128];
    float p = 0.f;
    for (int q = tid; q < D_HID; q += 128) p = fmaf(bm[q], wrow[q], p);
    red[tid] = p;
    __syncthreads();
    for (int off = 64; off > 0; off >>= 1) {
        if (tid < off) red[tid] += red[tid + off];
        __syncthreads();
    }
    if (tid == 0) {
        float base = bih[g*D_HID + j] + red[0];
        if (g < 2) base += bhh[g*D_HID + j];
        bc[(dir*3+g)*320 + j] = base;
        if (g == 2) bhhn[dir*320 + j] = bhh[2*D_HID + j];
    }
}

// ---------------- KW: Wout -> [320][640] bf16 (cols 0-299 = W[:,0:300], 320-619 = W[:,300:600], else 0);
//                     Wnode -> [320][128] bf16 (zero-padded) ----------------
__global__ __launch_bounds__(256)
void kW(const float* __restrict__ Wout, const float* __restrict__ Wnode,
        u16* __restrict__ Woutbf, u16* __restrict__ Wnbf)
{
    int idx = blockIdx.x*256 + threadIdx.x;
    if (idx < 320*640) {
        int j = idx / 640, k = idx % 640;
        float v = 0.f;
        if (j < D_HID) {
            if (k < D_HID)                 v = Wout[(size_t)j*600 + k];
            else if (k >= 320 && k < 620)  v = Wout[(size_t)j*600 + (k - 20)];
        }
        Woutbf[idx] = f2bf(v);
    } else {
        int i2 = idx - 320*640;
        if (i2 < 320*128) {
            int j = i2 >> 7, k = i2 & 127;
            float v = (j < D_HID && k < D_NODE) ? Wnode[(size_t)j*D_NODE + k] : 0.f;
            Wnbf[i2] = f2bf(v);
        }
    }
}

// ---------------- KA: gather+mean -> Abf bf16 [65536][128]; nodes -> Nbf bf16 [32768][128]
// One WAVE per row: lane l writes u32 col l (256 B coalesced store). ----------------
__global__ __launch_bounds__(256)
void kA(const float* __restrict__ nodes, const int* __restrict__ trip,
        u32* __restrict__ Abf, u32* __restrict__ Nbf)
{
    int wid  = (blockIdx.x*256 + threadIdx.x) >> 6;
    int nw   = (gridDim.x*256) >> 6;
    int lane = threadIdx.x & 63;
    for (int r = wid; r < 98304; r += nw) {
        if (r < 65536) {
            int b = r >> 9;
            int h  = trip[(size_t)r*3];
            int t2 = trip[(size_t)r*3 + 2];
            const float* nh = nodes + ((size_t)b*NNODE + h)*D_NODE;
            const float* nt = nodes + ((size_t)b*NNODE + t2)*D_NODE;
            u32 v = 0;
            if (lane < 50) {
                float2 a = *(const float2*)(nh + lane*2);
                float2 c = *(const float2*)(nt + lane*2);
                v = pack_bf(0.5f*(a.x + c.x), 0.5f*(a.y + c.y));
            }
            Abf[(size_t)r*64 + lane] = v;
        } else {
            int q = r - 65536;
            u32 v = 0;
            if (lane < 50) {
                float2 a = *(const float2*)(nodes + (size_t)q*D_NODE + lane*2);
                v = pack_bf(a.x, a.y);
            }
            Nbf[(size_t)q*64 + lane] = v;
        }
    }
}

// ---------------- KC: ctx -> bf16 padded [32768][320], uint4-vectorized ----------------
__global__ __launch_bounds__(256)
void kC(const float* __restrict__ ctx, u32* __restrict__ Cbf)
{
    int idx = blockIdx.x*256 + threadIdx.x;     // over 32768*40 uint4 groups
    int r = idx / 40, cp = idx % 40;
    int col = cp*8;
    uint4 v = {0,0,0,0};
    if (col < D_HID) {
        const float* base = ctx + (size_t)r*D_HID + col;
        float4 f0 = *(const float4*)base;
        v.x = pack_bf(f0.x, f0.y); v.y = pack_bf(f0.z, f0.w);
        if (col + 8 <= D_HID) {
            float4 f1 = *(const float4*)(base + 4);
            v.z = pack_bf(f1.x, f1.y); v.w = pack_bf(f1.z, f1.w);
        }
    }
    *(uint4*)(Cbf + (size_t)r*160 + cp*4) = v;
}

// ---------------- K1: GRU GEMM. One block = 32 rows x ALL 640 cols (10 slices in-loop).
// A fragments direct global->VGPR (no LDS, no barrier). grid 1024/half; UNFORCED register
// allocation (~120 VGPR) -> 4 blocks/CU organically. R5's spill came from forcing min-waves. ----------------
__global__ __launch_bounds__(256)
void k1_gru(const u16* __restrict__ Abf, const u16* __restrict__ W4bf,
            const float* __restrict__ bc, const float* __restrict__ bhhn,
            u16* __restrict__ H)
{
    int tid = threadIdx.x;
    int lane = tid & 63, w = tid >> 6;
    int l15 = lane & 15, lq = lane >> 4;
    int m0 = blockIdx.x * 32;

    // A fragments straight from global (L2/L3-resident after kA) — natural MFMA layout
    bf16x8 af[2][4];
    #pragma unroll
    for (int ms = 0; ms < 2; ++ms)
        #pragma unroll
        for (int ks = 0; ks < 4; ++ks)
            af[ms][ks] = *(const bf16x8*)(Abf + ((size_t)(m0 + ms*16 + l15))*128 + ks*32 + lq*8);

    #pragma unroll
    for (int st = 0; st < 10; ++st) {
        const int dir = (st < 5) ? 0 : 1;
        const int jg  = (st < 5) ? st : st - 5;
        const int j0w = jg*64 + w*16;
        const int j = j0w + l15;
        const u16* Wb = W4bf + (size_t)dir*3*320*128;

        bf16x8 bfr[3][4];
        #pragma unroll
        for (int g = 0; g < 3; ++g)
            #pragma unroll
            for (int ks = 0; ks < 4; ++ks)
                bfr[g][ks] = *(const bf16x8*)(Wb + ((size_t)(g*320 + j0w + l15))*128 + ks*32 + lq*8);

        f32x4 acc[2][3];
        #pragma unroll
        for (int ms = 0; ms < 2; ++ms)
            #pragma unroll
            for (int g = 0; g < 3; ++g)
                acc[ms][g] = (f32x4){0.f,0.f,0.f,0.f};

        #pragma unroll
        for (int ms = 0; ms < 2; ++ms)
            #pragma unroll
            for (int ks = 0; ks < 4; ++ks) {
                acc[ms][0] = __builtin_amdgcn_mfma_f32_16x16x32_bf16(af[ms][ks], bfr[0][ks], acc[ms][0], 0,0,0);
                acc[ms][1] = __builtin_amdgcn_mfma_f32_16x16x32_bf16(af[ms][ks], bfr[1][ks], acc[ms][1], 0,0,0);
                acc[ms][2] = __builtin_amdgcn_mfma_f32_16x16x32_bf16(af[ms][ks], bfr[2][ks], acc[ms][2], 0,0,0);
            }

        float bcr = bc[(dir*3+0)*320 + j];
        float bcz = bc[(dir*3+1)*320 + j];
        float bcn = bc[(dir*3+2)*320 + j];
        float bn2 = bhhn[dir*320 + j];
        bool ok = (j < D_HID);
        #pragma unroll
        for (int ms = 0; ms < 2; ++ms)
            #pragma unroll
            for (int i = 0; i < 4; ++i) {
                float r = fsig(acc[ms][0][i] + bcr);
                float z = fsig(acc[ms][1][i] + bcz);
                float n = ftanh(acc[ms][2][i] + bcn + r*bn2);
                float h = (1.f - z)*n;
                H[(size_t)(m0 + ms*16 + lq*4 + i)*640 + dir*320 + j] = ok ? f2bf(h) : (u16)0;
            }
    }
}

// ---------------- K2: Hid = tanh(H @ Wout^T + bout). One block = 64 rows x ALL 320 cols,
// K=640 streamed in 10 chunks of 64 through LDS (cross-wave tile sharing). H read exactly once. ----------------
__global__ __launch_bounds__(256, 2)
void k2_out(const u16* __restrict__ H, const u16* __restrict__ Woutbf,
            const float* __restrict__ bout, u16* __restrict__ Hid)
{
    __shared__ __attribute__((aligned(16))) char smem[8192];
    int tid = threadIdx.x;
    int lane = tid & 63, w = tid >> 6;      // w = j-quarter (80 cols each)
    int l15 = lane & 15, lq = lane >> 4;
    int m0 = blockIdx.x * 64;

    f32x4 acc[4][5];
    #pragma unroll
    for (int ms = 0; ms < 4; ++ms)
        #pragma unroll
        for (int jj = 0; jj < 5; ++jj)
            acc[ms][jj] = (f32x4){0.f,0.f,0.f,0.f};

    for (int c = 0; c < 10; ++c) {
        // stage chunk [64 rows][64 k] -> 8 fragment tiles (pm 0..3 x pk 0..1)
        #pragma unroll
        for (int r = 0; r < 2; ++r) {
            int p = w*2 + r, pm = p >> 1, pk = p & 1;
            gload_lds16(H + ((size_t)(m0 + pm*16 + l15))*640 + c*64 + pk*32 + lq*8,
                        smem + (size_t)(p*64)*16);
        }
        __syncthreads();
        #pragma unroll
        for (int pk = 0; pk < 2; ++pk) {
            bf16x8 bb[5];
            #pragma unroll
            for (int jj = 0; jj < 5; ++jj)
                bb[jj] = *(const bf16x8*)(Woutbf + ((size_t)(w*80 + jj*16 + l15))*640 + c*64 + pk*32 + lq*8);
            #pragma unroll
            for (int ms = 0; ms < 4; ++ms) {
                bf16x8 a = *(const bf16x8*)(smem + (size_t)(((ms*2+pk)*64 + lane))*16);
                #pragma unroll
                for (int jj = 0; jj < 5; ++jj)
                    acc[ms][jj] = __builtin_amdgcn_mfma_f32_16x16x32_bf16(a, bb[jj], acc[ms][jj], 0,0,0);
            }
        }
        __syncthreads();
    }

    #pragma unroll
    for (int jj = 0; jj < 5; ++jj) {
        int j = w*80 + jj*16 + l15;                 // < 320 always
        bool real = (j < D_HID);
        float bo = real ? bout[j] : 0.f;
        #pragma unroll
        for (int ms = 0; ms < 4; ++ms)
            #pragma unroll
            for (int i = 0; i < 4; ++i) {
                u16 v = real ? f2bf(ftanh(acc[ms][jj][i] + bo)) : (u16)0;
                Hid[(size_t)(m0 + ms*16 + lq*4 + i)*320 + j] = v;
            }
    }
}

// ---------------- K3: fused scores + softmax + partial-alpha.
// 1-D grid of 512, XCD-swizzled: all 4 m-blocks of a batch share id%8 -> same XCD L2. ----------------
__global__ __launch_bounds__(256, 2)
void k3_attn(const u16* __restrict__ Cbf, const u16* __restrict__ Hid,
             float* __restrict__ alphap)
{
    __shared__ char smemA[4096];       // 4 m-groups x 64 x 16 B
    __shared__ char smemB[32768];      // 32 t-groups x 64 x 16 B
    __shared__ float rmax[64*4], rsum[64*4];
    int tid = threadIdx.x;
    int lane = tid & 63, w = tid >> 6;
    int l15 = lane & 15, lq = lane >> 4;
    // id = xcd + 8*s ; s = bq*4 + mblk ; b = bq*8 + xcd
    int id = blockIdx.x;
    int xcd = id & 7, s = id >> 3;
    int bq = s >> 2, mblk = s & 3;
    int b = bq*8 + xcd;
    const u16* Ab = Cbf + ((size_t)b*LQn + mblk*64)*320;
    const u16* Bb = Hid + ((size_t)b*TSEQ)*320;

    f32x4 acc[4][8];
    #pragma unroll
    for (int ms = 0; ms < 4; ++ms)
        #pragma unroll
        for (int g = 0; g < 8; ++g)
            acc[ms][g] = (f32x4){0,0,0,0};

    for (int ks = 0; ks < 10; ++ks) {
        gload_lds16(Ab + ((size_t)(w*16 + l15))*320 + ks*32 + lq*8,
                    smemA + (size_t)(w*64)*16);
        #pragma unroll
        for (int i = 0; i < 8; ++i) {
            int nt = w*8 + i;
            gload_lds16(Bb + ((size_t)(nt*16 + l15))*320 + ks*32 + lq*8,
                        smemB + (size_t)(nt*64)*16);
        }
        __syncthreads();
        bf16x8 afr[4];
        #pragma unroll
        for (int ms = 0; ms < 4; ++ms)
            afr[ms] = *(const bf16x8*)(smemA + (size_t)((ms*64 + lane))*16);
        #pragma unroll
        for (int i = 0; i < 8; ++i) {
            bf16x8 bfr = *(const bf16x8*)(smemB + (size_t)(((w*8+i)*64 + lane))*16);
            #pragma unroll
            for (int ms = 0; ms < 4; ++ms)
                acc[ms][i] = __builtin_amdgcn_mfma_f32_16x16x32_bf16(afr[ms], bfr, acc[ms][i], 0,0,0);
        }
        __syncthreads();
    }

    #pragma unroll
    for (int ms = 0; ms < 4; ++ms)
        #pragma unroll
        for (int i = 0; i < 4; ++i) {
            float m = acc[ms][0][i];
            #pragma unroll
            for (int g = 1; g < 8; ++g) m = fmaxf(m, acc[ms][g][i]);
            m = fmaxf(m, __shfl_xor(m, 1));
            m = fmaxf(m, __shfl_xor(m, 2));
            m = fmaxf(m, __shfl_xor(m, 4));
            m = fmaxf(m, __shfl_xor(m, 8));
            if (l15 == 0) rmax[(ms*16 + lq*4 + i)*4 + w] = m;
        }
    __syncthreads();
    float mfin[4][4];
    #pragma unroll
    for (int ms = 0; ms < 4; ++ms)
        #pragma unroll
        for (int i = 0; i < 4; ++i) {
            float4 mv = *(const float4*)&rmax[(ms*16 + lq*4 + i)*4];
            mfin[ms][i] = fmaxf(fmaxf(mv.x, mv.y), fmaxf(mv.z, mv.w));
        }
    #pragma unroll
    for (int ms = 0; ms < 4; ++ms)
        #pragma unroll
        for (int i = 0; i < 4; ++i) {
            float s2 = 0.f;
            #pragma unroll
            for (int g = 0; g < 8; ++g) {
                float e = __expf(acc[ms][g][i] - mfin[ms][i]);
                acc[ms][g][i] = e;
                s2 += e;
            }
            s2 += __shfl_xor(s2, 1);
            s2 += __shfl_xor(s2, 2);
            s2 += __shfl_xor(s2, 4);
            s2 += __shfl_xor(s2, 8);
            if (l15 == 0) rsum[(ms*16 + lq*4 + i)*4 + w] = s2;
        }
    __syncthreads();
    float inv[4][4];
    #pragma unroll
    for (int ms = 0; ms < 4; ++ms)
        #pragma unroll
        for (int i = 0; i < 4; ++i) {
            float4 sv = *(const float4*)&rsum[(ms*16 + lq*4 + i)*4];
            inv[ms][i] = __builtin_amdgcn_rcpf(sv.x + sv.y + sv.z + sv.w);
        }
    float* ap = alphap + ((size_t)b*4 + mblk)*TSEQ;
    #pragma unroll
    for (int g = 0; g < 8; ++g) {
        float c = 0.f;
        #pragma unroll
        for (int ms = 0; ms < 4; ++ms)
            #pragma unroll
            for (int i = 0; i < 4; ++i)
                c = fmaf(acc[ms][g][i], inv[ms][i], c);
        c += __shfl_xor(c, 16);
        c += __shfl_xor(c, 32);
        if (lq == 0) ap[w*128 + g*16 + l15] = c;
    }
}

// ---------------- K4: rep = (sum of 4 partial alphas) @ Hid ; layernorm -> path_feature
// 640 threads, t-range split in two halves; dual accumulators halve the dep chain. ----------------
__global__ __launch_bounds__(640)
void k4_rep(const float* __restrict__ alphap, const u16* __restrict__ Hid,
            const float* __restrict__ gamma, const float* __restrict__ beta,
            float* __restrict__ outP)
{
    __shared__ float al[512];
    __shared__ float part[320];
    __shared__ float rs[10], rss[10];
    int tid = threadIdx.x, b = blockIdx.x;
    const float* ap = alphap + (size_t)b*4*TSEQ;
    for (int i = tid; i < 512; i += 640)
        al[i] = ap[i] + ap[512 + i] + ap[1024 + i] + ap[1536 + i];
    __syncthreads();
    int half = (tid >= 320) ? 1 : 0;
    int c = tid - half*320;
    float acc = 0.f;
    if (c < D_HID) {
        const u16* hp = Hid + (size_t)b*TSEQ*320 + (size_t)half*256*320 + c;
        float a0 = 0.f, a1 = 0.f;
        #pragma unroll 4
        for (int t = 0; t < 256; t += 2) {
            a0 = fmaf(al[half*256 + t],     bf2f(hp[(size_t)t*320]),       a0);
            a1 = fmaf(al[half*256 + t + 1], bf2f(hp[(size_t)(t+1)*320]),   a1);
        }
        acc = a0 + a1;
    }
    if (half) part[c] = acc;
    __syncthreads();
    float tot = 0.f;
    if (!half) tot = acc + part[c];
    float v = (!half && c < D_HID) ? tot : 0.f;
    float s = v, q = v*v;
    #pragma unroll
    for (int off = 32; off > 0; off >>= 1) { s += __shfl_xor(s, off, 64); q += __shfl_xor(q, off, 64); }
    if ((tid & 63) == 0) { rs[tid >> 6] = s; rss[tid >> 6] = q; }
    __syncthreads();
    float S = rs[0]+rs[1]+rs[2]+rs[3]+rs[4]+rs[5]+rs[6]+rs[7]+rs[8]+rs[9];
    float Q = rss[0]+rss[1]+rss[2]+rss[3]+rss[4]+rss[5]+rss[6]+rss[7]+rss[8]+rss[9];
    float mu = S * (1.f/300.f);
    float var = Q * (1.f/300.f) - mu*mu;
    if (!half && c < D_HID)
        outP[(size_t)b*D_HID + c] = (tot - mu) * rsqrtf(var + 1e-5f) * gamma[c] + beta[c];
}

// ---------------- K5: node_feature = nodes @ Wnode^T + bnode via MFMA (fp32 out) ----------------
__global__ __launch_bounds__(256)
void k5_node(const u16* __restrict__ Nbf, const u16* __restrict__ Wnbf,
             const float* __restrict__ bn, float* __restrict__ outN)
{
    __shared__ char smem[16384];
    int tid = threadIdx.x;
    int lane = tid & 63, w = tid >> 6;
    int l15 = lane & 15, lq = lane >> 4;
    int m0 = blockIdx.x * 64;
    int j0w = blockIdx.y*64 + w*16;

    bf16x8 bw[4];
    #pragma unroll
    for (int ks = 0; ks < 4; ++ks)
        bw[ks] = *(const bf16x8*)(Wnbf + ((size_t)(j0w + l15))*128 + ks*32 + lq*8);

    #pragma unroll
    for (int ks = 0; ks < 4; ++ks) {
        const u16* g = Nbf + ((size_t)(m0 + w*16 + l15))*128 + ks*32 + lq*8;
        gload_lds16(g, smem + (size_t)((w*4 + ks)*64)*16);
    }
    __syncthreads();

    f32x4 acc[4];
    #pragma unroll
    for (int ms = 0; ms < 4; ++ms) acc[ms] = (f32x4){0,0,0,0};
    #pragma unroll
    for (int ms = 0; ms < 4; ++ms)
        #pragma unroll
        for (int ks = 0; ks < 4; ++ks) {
            bf16x8 a = *(const bf16x8*)(smem + (size_t)(((ms*4+ks)*64 + lane))*16);
            acc[ms] = __builtin_amdgcn_mfma_f32_16x16x32_bf16(a, bw[ks], acc[ms], 0,0,0);
        }

    int j = j0w + l15;
    if (j < D_HID) {
        float bo = bn[j];
        #pragma unroll
        for (int ms = 0; ms < 4; ++ms)
            #pragma unroll
            for (int i = 0; i < 4; ++i)
                outN[(size_t)(m0 + ms*16 + lq*4 + i)*D_HID + j] = acc[ms][i] + bo;
    }
}

extern "C" void kernel_launch(void* const* d_in, const int* in_sizes, int n_in,
                              void* d_out, int out_size, void* d_ws, size_t ws_size,
                              hipStream_t stream) {
    const float* nodes  = (const float*)d_in[0];
    const float* ctx    = (const float*)d_in[1];
    const int*   trip   = (const int*)d_in[2];
    const float* Wm     = (const float*)d_in[4];
    const float* bm     = (const float*)d_in[5];
    const float* Wihf   = (const float*)d_in[6];
    const float* bihf   = (const float*)d_in[7];
    const float* bhhf   = (const float*)d_in[8];
    const float* Wihb   = (const float*)d_in[9];
    const float* bihb   = (const float*)d_in[10];
    const float* bhhb   = (const float*)d_in[11];
    const float* Wout   = (const float*)d_in[12];
    const float* bout   = (const float*)d_in[13];
    const float* Wnode  = (const float*)d_in[14];
    const float* bnode  = (const float*)d_in[15];
    const float* gamma  = (const float*)d_in[16];
    const float* beta   = (const float*)d_in[17];
    float* out = (float*)d_out;

    char* ws = (char*)d_ws;
    u16*   W4bf   = (u16*)(ws);                         //    491,520 B
    u16*   Woutbf = (u16*)(ws + 491520);                //    409,600 B  [320][640]
    u16*   Wnbf   = (u16*)(ws + 901120);                //     81,920 B
    float* bc     = (float*)(ws + 983040);              //      7,680 B
    float* bhhn   = (float*)(ws + 990720);              //      2,560 B
    u32*   Abf    = (u32*)(ws + 1048576);               // 16,777,216 B  [65536][64 u32]
    u32*   Nbf    = (u32*)(ws + 17825792ull);           //  8,388,608 B  [32768][64 u32]
    u16*   Hhalf  = (u16*)(ws + 26214400ull);           // 41,943,040 B  [32768][640] (per half)
    u32*   Cbf    = (u32*)(ws + 26214400ull);           // overlay on Hhalf (after 2nd k2): 20,971,520 B
    u16*   Hid    = (u16*)(ws + 68157440ull);           // 41,943,040 B  [65536][320]
    float* alphap = (float*)(ws + 110100480ull);        //  1,048,576 B -> total 111,149,056 B

    k0_prep<<<dim3(320,3,2), 128, 0, stream>>>(Wm,bm,Wihf,bihf,bhhf,Wihb,bihb,bhhb,W4bf,bc,bhhn);
    kW     <<<960,  256, 0, stream>>>(Wout,Wnode,Woutbf,Wnbf);
    kA     <<<1024, 256, 0, stream>>>(nodes,trip,Abf,Nbf);

    for (int h = 0; h < 2; ++h) {
        const u16* Ah   = (const u16*)Abf + (size_t)h*32768*128;
        u16*       Hidh = Hid + (size_t)h*32768*320;
        k1_gru<<<1024, 256, 0, stream>>>(Ah, W4bf, bc, bhhn, Hhalf);
        k2_out<<<512,  256, 0, stream>>>(Hhalf, Woutbf, bout, Hidh);
    }

    k5_node<<<dim3(512,5), 256, 0, stream>>>((const u16*)Nbf,Wnbf,bnode,out + 38400);
    kC     <<<5120, 256, 0, stream>>>(ctx, Cbf);                // overlays Hhalf (dead)
    k3_attn<<<512,         256, 0, stream>>>((const u16*)Cbf, Hid, alphap);
    k4_rep <<<128,         640, 0, stream>>>(alphap,Hid,gamma,beta,out);
    hipMemsetAsync(out + 38400 + 9830400, 0, 32768*sizeof(float), stream);
}

// Round 10
// 403.251 us; speedup vs baseline: 1.0963x; 1.0963x over previous
//
#include <hip/hip_runtime.h>
#include <math.h>

#define D_NODE 100
#define D_HID  300
static const int TSEQ = 512, LQn = 256, NNODE = 256;

typedef unsigned int u32;
typedef unsigned short u16;
typedef __attribute__((ext_vector_type(8))) short bf16x8;   // 8 bf16 = 4 VGPRs
typedef __attribute__((ext_vector_type(4))) float f32x4;

__device__ __forceinline__ float bf2f(u16 v){ return __uint_as_float(((u32)v) << 16); }
__device__ __forceinline__ u16 f2bf(float f){
    u32 u = __float_as_uint(f);
    return (u16)((u + 0x7fffu + ((u >> 16) & 1u)) >> 16);
}
__device__ __forceinline__ u32 pack_bf(float lo, float hi){
    return ((u32)f2bf(lo)) | (((u32)f2bf(hi)) << 16);
}
__device__ __forceinline__ void gload_lds16(const void* g, void* l){
    __builtin_amdgcn_global_load_lds(
        (const __attribute__((address_space(1))) u32*)g,
        (__attribute__((address_space(3))) u32*)l, 16, 0, 0);
}
// fast sigmoid / tanh on v_exp_f32 + v_rcp_f32 (saturate correctly at +/-inf)
__device__ __forceinline__ float fsig(float x){
    return __builtin_amdgcn_rcpf(1.f + __expf(-x));
}
__device__ __forceinline__ float ftanh(float x){
    return 1.f - 2.f*__builtin_amdgcn_rcpf(1.f + __expf(2.f*x));
}

// ---------------- K0: fold W_mean into GRU weights -> W4bf bf16 [dir][gate][320 j][128 k] ----------------
__global__ __launch_bounds__(128)
void k0_prep(const float* __restrict__ Wm, const float* __restrict__ bm,
             const float* __restrict__ Wihf, const float* __restrict__ bihf, const float* __restrict__ bhhf,
             const float* __restrict__ Wihb, const float* __restrict__ bihb, const float* __restrict__ bhhb,
             u16* __restrict__ W4bf, float* __restrict__ bc, float* __restrict__ bhhn)
{
    int j = blockIdx.x, g = blockIdx.y, dir = blockIdx.z;
    int tid = threadIdx.x;
    u16* wout = W4bf + ((size_t)((dir*3+g)*320 + j))*128;
    if (j >= D_HID) {
        wout[tid] = 0;
        if (tid == 0) { bc[(dir*3+g)*320 + j] = 0.f; if (g==2) bhhn[dir*320+j] = 0.f; }
        return;
    }
    const float* Wih = dir ? Wihb : Wihf;
    const float* bih = dir ? bihb : bihf;
    const float* bhh = dir ? bhhb : bhhf;
    const float* wrow = Wih + (size_t)(g*D_HID + j)*D_HID;
    int k = tid;
    float s = 0.f;
    if (k < D_NODE)
        for (int q = 0; q < D_HID; ++q)
            s = fmaf(wrow[q], Wm[q*D_NODE + k], s);
    wout[k] = f2bf(k < D_NODE ? s : 0.f);

    __shared__ float red[128];
    float p = 0.f;
    for (int q = tid; q < D_HID; q += 128) p = fmaf(bm[q], wrow[q], p);
    red[tid] = p;
    __syncthreads();
    for (int off = 64; off > 0; off >>= 1) {
        if (tid < off) red[tid] += red[tid + off];
        __syncthreads();
    }
    if (tid == 0) {
        float base = bih[g*D_HID + j] + red[0];
        if (g < 2) base += bhh[g*D_HID + j];
        bc[(dir*3+g)*320 + j] = base;
        if (g == 2) bhhn[dir*320 + j] = bhh[2*D_HID + j];
    }
}

// ---------------- KW: Wout -> [320][640] bf16 (cols 0-299 = W[:,0:300], 320-619 = W[:,300:600], else 0);
//                     Wnode -> [320][128] bf16 (zero-padded) ----------------
__global__ __launch_bounds__(256)
void kW(const float* __restrict__ Wout, const float* __restrict__ Wnode,
        u16* __restrict__ Woutbf, u16* __restrict__ Wnbf)
{
    int idx = blockIdx.x*256 + threadIdx.x;
    if (idx < 320*640) {
        int j = idx / 640, k = idx % 640;
        float v = 0.f;
        if (j < D_HID) {
            if (k < D_HID)                 v = Wout[(size_t)j*600 + k];
            else if (k >= 320 && k < 620)  v = Wout[(size_t)j*600 + (k - 20)];
        }
        Woutbf[idx] = f2bf(v);
    } else {
        int i2 = idx - 320*640;
        if (i2 < 320*128) {
            int j = i2 >> 7, k = i2 & 127;
            float v = (j < D_HID && k < D_NODE) ? Wnode[(size_t)j*D_NODE + k] : 0.f;
            Wnbf[i2] = f2bf(v);
        }
    }
}

// ---------------- KA: gather+mean -> Abf bf16 [65536][128]; nodes -> Nbf bf16 [32768][128]
// One WAVE per row: lane l writes u32 col l (256 B coalesced store). ----------------
__global__ __launch_bounds__(256)
void kA(const float* __restrict__ nodes, const int* __restrict__ trip,
        u32* __restrict__ Abf, u32* __restrict__ Nbf)
{
    int wid  = (blockIdx.x*256 + threadIdx.x) >> 6;
    int nw   = (gridDim.x*256) >> 6;
    int lane = threadIdx.x & 63;
    for (int r = wid; r < 98304; r += nw) {
        if (r < 65536) {
            int b = r >> 9;
            int h  = trip[(size_t)r*3];
            int t2 = trip[(size_t)r*3 + 2];
            const float* nh = nodes + ((size_t)b*NNODE + h)*D_NODE;
            const float* nt = nodes + ((size_t)b*NNODE + t2)*D_NODE;
            u32 v = 0;
            if (lane < 50) {
                float2 a = *(const float2*)(nh + lane*2);
                float2 c = *(const float2*)(nt + lane*2);
                v = pack_bf(0.5f*(a.x + c.x), 0.5f*(a.y + c.y));
            }
            Abf[(size_t)r*64 + lane] = v;
        } else {
            int q = r - 65536;
            u32 v = 0;
            if (lane < 50) {
                float2 a = *(const float2*)(nodes + (size_t)q*D_NODE + lane*2);
                v = pack_bf(a.x, a.y);
            }
            Nbf[(size_t)q*64 + lane] = v;
        }
    }
}

// ---------------- KC: ctx -> bf16 padded [32768][320], uint4-vectorized ----------------
__global__ __launch_bounds__(256)
void kC(const float* __restrict__ ctx, u32* __restrict__ Cbf)
{
    int idx = blockIdx.x*256 + threadIdx.x;     // over 32768*40 uint4 groups
    int r = idx / 40, cp = idx % 40;
    int col = cp*8;
    uint4 v = {0,0,0,0};
    if (col < D_HID) {
        const float* base = ctx + (size_t)r*D_HID + col;
        float4 f0 = *(const float4*)base;
        v.x = pack_bf(f0.x, f0.y); v.y = pack_bf(f0.z, f0.w);
        if (col + 8 <= D_HID) {
            float4 f1 = *(const float4*)(base + 4);
            v.z = pack_bf(f1.x, f1.y); v.w = pack_bf(f1.z, f1.w);
        }
    }
    *(uint4*)(Cbf + (size_t)r*160 + cp*4) = v;
}

// ---------------- K1: GRU GEMM. One block = 64 rows x ALL 640 output cols (10 slices in-loop).
// A fragments loaded DIRECTLY global->VGPR (no LDS, no barrier); W streamed from L2 per slice.
// 64-row shape is the measured optimum (32-row: 72 us, W-latency dominates; 64-row: ~46 us). ----------------
__global__ __launch_bounds__(256, 2)
void k1_gru(const u16* __restrict__ Abf, const u16* __restrict__ W4bf,
            const float* __restrict__ bc, const float* __restrict__ bhhn,
            u16* __restrict__ H)
{
    int tid = threadIdx.x;
    int lane = tid & 63, w = tid >> 6;
    int l15 = lane & 15, lq = lane >> 4;
    int m0 = blockIdx.x * 64;

    // A fragments straight from global (L2/L3-resident after kA) — natural MFMA layout
    bf16x8 af[4][4];
    #pragma unroll
    for (int ms = 0; ms < 4; ++ms)
        #pragma unroll
        for (int ks = 0; ks < 4; ++ks)
            af[ms][ks] = *(const bf16x8*)(Abf + ((size_t)(m0 + ms*16 + l15))*128 + ks*32 + lq*8);

    #pragma unroll
    for (int st = 0; st < 10; ++st) {
        const int dir = (st < 5) ? 0 : 1;
        const int jg  = (st < 5) ? st : st - 5;
        const int j0w = jg*64 + w*16;
        const int j = j0w + l15;
        const u16* Wb = W4bf + (size_t)dir*3*320*128;

        bf16x8 bfr[3][4];
        #pragma unroll
        for (int g = 0; g < 3; ++g)
            #pragma unroll
            for (int ks = 0; ks < 4; ++ks)
                bfr[g][ks] = *(const bf16x8*)(Wb + ((size_t)(g*320 + j0w + l15))*128 + ks*32 + lq*8);

        f32x4 acc[4][3];
        #pragma unroll
        for (int ms = 0; ms < 4; ++ms)
            #pragma unroll
            for (int g = 0; g < 3; ++g)
                acc[ms][g] = (f32x4){0.f,0.f,0.f,0.f};

        #pragma unroll
        for (int ms = 0; ms < 4; ++ms)
            #pragma unroll
            for (int ks = 0; ks < 4; ++ks) {
                acc[ms][0] = __builtin_amdgcn_mfma_f32_16x16x32_bf16(af[ms][ks], bfr[0][ks], acc[ms][0], 0,0,0);
                acc[ms][1] = __builtin_amdgcn_mfma_f32_16x16x32_bf16(af[ms][ks], bfr[1][ks], acc[ms][1], 0,0,0);
                acc[ms][2] = __builtin_amdgcn_mfma_f32_16x16x32_bf16(af[ms][ks], bfr[2][ks], acc[ms][2], 0,0,0);
            }

        float bcr = bc[(dir*3+0)*320 + j];
        float bcz = bc[(dir*3+1)*320 + j];
        float bcn = bc[(dir*3+2)*320 + j];
        float bn2 = bhhn[dir*320 + j];
        bool ok = (j < D_HID);
        #pragma unroll
        for (int ms = 0; ms < 4; ++ms)
            #pragma unroll
            for (int i = 0; i < 4; ++i) {
                float r = fsig(acc[ms][0][i] + bcr);
                float z = fsig(acc[ms][1][i] + bcz);
                float n = ftanh(acc[ms][2][i] + bcn + r*bn2);
                float h = (1.f - z)*n;
                H[(size_t)(m0 + ms*16 + lq*4 + i)*640 + dir*320 + j] = ok ? f2bf(h) : (u16)0;
            }
    }
}

// ---------------- K2: Hid = tanh(H @ Wout^T + bout). One block = 64 rows x ALL 320 cols,
// K=640 streamed in 10 chunks of 64 through LDS (cross-wave tile sharing). H read exactly once. ----------------
__global__ __launch_bounds__(256, 2)
void k2_out(const u16* __restrict__ H, const u16* __restrict__ Woutbf,
            const float* __restrict__ bout, u16* __restrict__ Hid)
{
    __shared__ __attribute__((aligned(16))) char smem[8192];
    int tid = threadIdx.x;
    int lane = tid & 63, w = tid >> 6;      // w = j-quarter (80 cols each)
    int l15 = lane & 15, lq = lane >> 4;
    int m0 = blockIdx.x * 64;

    f32x4 acc[4][5];
    #pragma unroll
    for (int ms = 0; ms < 4; ++ms)
        #pragma unroll
        for (int jj = 0; jj < 5; ++jj)
            acc[ms][jj] = (f32x4){0.f,0.f,0.f,0.f};

    for (int c = 0; c < 10; ++c) {
        // stage chunk [64 rows][64 k] -> 8 fragment tiles (pm 0..3 x pk 0..1)
        #pragma unroll
        for (int r = 0; r < 2; ++r) {
            int p = w*2 + r, pm = p >> 1, pk = p & 1;
            gload_lds16(H + ((size_t)(m0 + pm*16 + l15))*640 + c*64 + pk*32 + lq*8,
                        smem + (size_t)(p*64)*16);
        }
        __syncthreads();
        #pragma unroll
        for (int pk = 0; pk < 2; ++pk) {
            bf16x8 bb[5];
            #pragma unroll
            for (int jj = 0; jj < 5; ++jj)
                bb[jj] = *(const bf16x8*)(Woutbf + ((size_t)(w*80 + jj*16 + l15))*640 + c*64 + pk*32 + lq*8);
            #pragma unroll
            for (int ms = 0; ms < 4; ++ms) {
                bf16x8 a = *(const bf16x8*)(smem + (size_t)(((ms*2+pk)*64 + lane))*16);
                #pragma unroll
                for (int jj = 0; jj < 5; ++jj)
                    acc[ms][jj] = __builtin_amdgcn_mfma_f32_16x16x32_bf16(a, bb[jj], acc[ms][jj], 0,0,0);
            }
        }
        __syncthreads();
    }

    #pragma unroll
    for (int jj = 0; jj < 5; ++jj) {
        int j = w*80 + jj*16 + l15;                 // < 320 always
        bool real = (j < D_HID);
        float bo = real ? bout[j] : 0.f;
        #pragma unroll
        for (int ms = 0; ms < 4; ++ms)
            #pragma unroll
            for (int i = 0; i < 4; ++i) {
                u16 v = real ? f2bf(ftanh(acc[ms][jj][i] + bo)) : (u16)0;
                Hid[(size_t)(m0 + ms*16 + lq*4 + i)*320 + j] = v;
            }
    }
}

// ---------------- K3: fused scores + softmax + partial-alpha.
// 1-D grid of 512, XCD-swizzled: all 4 m-blocks of a batch share id%8 -> same XCD L2. ----------------
__global__ __launch_bounds__(256, 2)
void k3_attn(const u16* __restrict__ Cbf, const u16* __restrict__ Hid,
             float* __restrict__ alphap)
{
    __shared__ char smemA[4096];       // 4 m-groups x 64 x 16 B
    __shared__ char smemB[32768];      // 32 t-groups x 64 x 16 B
    __shared__ float rmax[64*4], rsum[64*4];
    int tid = threadIdx.x;
    int lane = tid & 63, w = tid >> 6;
    int l15 = lane & 15, lq = lane >> 4;
    // id = xcd + 8*s ; s = bq*4 + mblk ; b = bq*8 + xcd
    int id = blockIdx.x;
    int xcd = id & 7, s = id >> 3;
    int bq = s >> 2, mblk = s & 3;
    int b = bq*8 + xcd;
    const u16* Ab = Cbf + ((size_t)b*LQn + mblk*64)*320;
    const u16* Bb = Hid + ((size_t)b*TSEQ)*320;

    f32x4 acc[4][8];
    #pragma unroll
    for (int ms = 0; ms < 4; ++ms)
        #pragma unroll
        for (int g = 0; g < 8; ++g)
            acc[ms][g] = (f32x4){0,0,0,0};

    for (int ks = 0; ks < 10; ++ks) {
        gload_lds16(Ab + ((size_t)(w*16 + l15))*320 + ks*32 + lq*8,
                    smemA + (size_t)(w*64)*16);
        #pragma unroll
        for (int i = 0; i < 8; ++i) {
            int nt = w*8 + i;
            gload_lds16(Bb + ((size_t)(nt*16 + l15))*320 + ks*32 + lq*8,
                        smemB + (size_t)(nt*64)*16);
        }
        __syncthreads();
        bf16x8 afr[4];
        #pragma unroll
        for (int ms = 0; ms < 4; ++ms)
            afr[ms] = *(const bf16x8*)(smemA + (size_t)((ms*64 + lane))*16);
        #pragma unroll
        for (int i = 0; i < 8; ++i) {
            bf16x8 bfr = *(const bf16x8*)(smemB + (size_t)(((w*8+i)*64 + lane))*16);
            #pragma unroll
            for (int ms = 0; ms < 4; ++ms)
                acc[ms][i] = __builtin_amdgcn_mfma_f32_16x16x32_bf16(afr[ms], bfr, acc[ms][i], 0,0,0);
        }
        __syncthreads();
    }

    #pragma unroll
    for (int ms = 0; ms < 4; ++ms)
        #pragma unroll
        for (int i = 0; i < 4; ++i) {
            float m = acc[ms][0][i];
            #pragma unroll
            for (int g = 1; g < 8; ++g) m = fmaxf(m, acc[ms][g][i]);
            m = fmaxf(m, __shfl_xor(m, 1));
            m = fmaxf(m, __shfl_xor(m, 2));
            m = fmaxf(m, __shfl_xor(m, 4));
            m = fmaxf(m, __shfl_xor(m, 8));
            if (l15 == 0) rmax[(ms*16 + lq*4 + i)*4 + w] = m;
        }
    __syncthreads();
    float mfin[4][4];
    #pragma unroll
    for (int ms = 0; ms < 4; ++ms)
        #pragma unroll
        for (int i = 0; i < 4; ++i) {
            float4 mv = *(const float4*)&rmax[(ms*16 + lq*4 + i)*4];
            mfin[ms][i] = fmaxf(fmaxf(mv.x, mv.y), fmaxf(mv.z, mv.w));
        }
    #pragma unroll
    for (int ms = 0; ms < 4; ++ms)
        #pragma unroll
        for (int i = 0; i < 4; ++i) {
            float s2 = 0.f;
            #pragma unroll
            for (int g = 0; g < 8; ++g) {
                float e = __expf(acc[ms][g][i] - mfin[ms][i]);
                acc[ms][g][i] = e;
                s2 += e;
            }
            s2 += __shfl_xor(s2, 1);
            s2 += __shfl_xor(s2, 2);
            s2 += __shfl_xor(s2, 4);
            s2 += __shfl_xor(s2, 8);
            if (l15 == 0) rsum[(ms*16 + lq*4 + i)*4 + w] = s2;
        }
    __syncthreads();
    float inv[4][4];
    #pragma unroll
    for (int ms = 0; ms < 4; ++ms)
        #pragma unroll
        for (int i = 0; i < 4; ++i) {
            float4 sv = *(const float4*)&rsum[(ms*16 + lq*4 + i)*4];
            inv[ms][i] = __builtin_amdgcn_rcpf(sv.x + sv.y + sv.z + sv.w);
        }
    float* ap = alphap + ((size_t)b*4 + mblk)*TSEQ;
    #pragma unroll
    for (int g = 0; g < 8; ++g) {
        float c = 0.f;
        #pragma unroll
        for (int ms = 0; ms < 4; ++ms)
            #pragma unroll
            for (int i = 0; i < 4; ++i)
                c = fmaf(acc[ms][g][i], inv[ms][i], c);
        c += __shfl_xor(c, 16);
        c += __shfl_xor(c, 32);
        if (lq == 0) ap[w*128 + g*16 + l15] = c;
    }
}

// ---------------- K4: rep = (sum of 4 partial alphas) @ Hid ; layernorm -> path_feature
// 640 threads, t-range split in two halves; dual accumulators halve the dep chain. ----------------
__global__ __launch_bounds__(640)
void k4_rep(const float* __restrict__ alphap, const u16* __restrict__ Hid,
            const float* __restrict__ gamma, const float* __restrict__ beta,
            float* __restrict__ outP)
{
    __shared__ float al[512];
    __shared__ float part[320];
    __shared__ float rs[10], rss[10];
    int tid = threadIdx.x, b = blockIdx.x;
    const float* ap = alphap + (size_t)b*4*TSEQ;
    for (int i = tid; i < 512; i += 640)
        al[i] = ap[i] + ap[512 + i] + ap[1024 + i] + ap[1536 + i];
    __syncthreads();
    int half = (tid >= 320) ? 1 : 0;
    int c = tid - half*320;
    float acc = 0.f;
    if (c < D_HID) {
        const u16* hp = Hid + (size_t)b*TSEQ*320 + (size_t)half*256*320 + c;
        float a0 = 0.f, a1 = 0.f;
        #pragma unroll 4
        for (int t = 0; t < 256; t += 2) {
            a0 = fmaf(al[half*256 + t],     bf2f(hp[(size_t)t*320]),       a0);
            a1 = fmaf(al[half*256 + t + 1], bf2f(hp[(size_t)(t+1)*320]),   a1);
        }
        acc = a0 + a1;
    }
    if (half) part[c] = acc;
    __syncthreads();
    float tot = 0.f;
    if (!half) tot = acc + part[c];
    float v = (!half && c < D_HID) ? tot : 0.f;
    float s = v, q = v*v;
    #pragma unroll
    for (int off = 32; off > 0; off >>= 1) { s += __shfl_xor(s, off, 64); q += __shfl_xor(q, off, 64); }
    if ((tid & 63) == 0) { rs[tid >> 6] = s; rss[tid >> 6] = q; }
    __syncthreads();
    float S = rs[0]+rs[1]+rs[2]+rs[3]+rs[4]+rs[5]+rs[6]+rs[7]+rs[8]+rs[9];
    float Q = rss[0]+rss[1]+rss[2]+rss[3]+rss[4]+rss[5]+rss[6]+rss[7]+rss[8]+rss[9];
    float mu = S * (1.f/300.f);
    float var = Q * (1.f/300.f) - mu*mu;
    if (!half && c < D_HID)
        outP[(size_t)b*D_HID + c] = (tot - mu) * rsqrtf(var + 1e-5f) * gamma[c] + beta[c];
}

// ---------------- K5: node_feature = nodes @ Wnode^T + bnode via MFMA (fp32 out) ----------------
__global__ __launch_bounds__(256)
void k5_node(const u16* __restrict__ Nbf, const u16* __restrict__ Wnbf,
             const float* __restrict__ bn, float* __restrict__ outN)
{
    __shared__ char smem[16384];
    int tid = threadIdx.x;
    int lane = tid & 63, w = tid >> 6;
    int l15 = lane & 15, lq = lane >> 4;
    int m0 = blockIdx.x * 64;
    int j0w = blockIdx.y*64 + w*16;

    bf16x8 bw[4];
    #pragma unroll
    for (int ks = 0; ks < 4; ++ks)
        bw[ks] = *(const bf16x8*)(Wnbf + ((size_t)(j0w + l15))*128 + ks*32 + lq*8);

    #pragma unroll
    for (int ks = 0; ks < 4; ++ks) {
        const u16* g = Nbf + ((size_t)(m0 + w*16 + l15))*128 + ks*32 + lq*8;
        gload_lds16(g, smem + (size_t)((w*4 + ks)*64)*16);
    }
    __syncthreads();

    f32x4 acc[4];
    #pragma unroll
    for (int ms = 0; ms < 4; ++ms) acc[ms] = (f32x4){0,0,0,0};
    #pragma unroll
    for (int ms = 0; ms < 4; ++ms)
        #pragma unroll
        for (int ks = 0; ks < 4; ++ks) {
            bf16x8 a = *(const bf16x8*)(smem + (size_t)(((ms*4+ks)*64 + lane))*16);
            acc[ms] = __builtin_amdgcn_mfma_f32_16x16x32_bf16(a, bw[ks], acc[ms], 0,0,0);
        }

    int j = j0w + l15;
    if (j < D_HID) {
        float bo = bn[j];
        #pragma unroll
        for (int ms = 0; ms < 4; ++ms)
            #pragma unroll
            for (int i = 0; i < 4; ++i)
                outN[(size_t)(m0 + ms*16 + lq*4 + i)*D_HID + j] = acc[ms][i] + bo;
    }
}

extern "C" void kernel_launch(void* const* d_in, const int* in_sizes, int n_in,
                              void* d_out, int out_size, void* d_ws, size_t ws_size,
                              hipStream_t stream) {
    const float* nodes  = (const float*)d_in[0];
    const float* ctx    = (const float*)d_in[1];
    const int*   trip   = (const int*)d_in[2];
    const float* Wm     = (const float*)d_in[4];
    const float* bm     = (const float*)d_in[5];
    const float* Wihf   = (const float*)d_in[6];
    const float* bihf   = (const float*)d_in[7];
    const float* bhhf   = (const float*)d_in[8];
    const float* Wihb   = (const float*)d_in[9];
    const float* bihb   = (const float*)d_in[10];
    const float* bhhb   = (const float*)d_in[11];
    const float* Wout   = (const float*)d_in[12];
    const float* bout   = (const float*)d_in[13];
    const float* Wnode  = (const float*)d_in[14];
    const float* bnode  = (const float*)d_in[15];
    const float* gamma  = (const float*)d_in[16];
    const float* beta   = (const float*)d_in[17];
    float* out = (float*)d_out;

    char* ws = (char*)d_ws;
    u16*   W4bf   = (u16*)(ws);                         //    491,520 B
    u16*   Woutbf = (u16*)(ws + 491520);                //    409,600 B  [320][640]
    u16*   Wnbf   = (u16*)(ws + 901120);                //     81,920 B
    float* bc     = (float*)(ws + 983040);              //      7,680 B
    float* bhhn   = (float*)(ws + 990720);              //      2,560 B
    u32*   Abf    = (u32*)(ws + 1048576);               // 16,777,216 B  [65536][64 u32]
    u32*   Nbf    = (u32*)(ws + 17825792ull);           //  8,388,608 B  [32768][64 u32]
    u16*   Hhalf  = (u16*)(ws + 26214400ull);           // 41,943,040 B  [32768][640] (per half)
    u32*   Cbf    = (u32*)(ws + 26214400ull);           // overlay on Hhalf (after 2nd k2): 20,971,520 B
    u16*   Hid    = (u16*)(ws + 68157440ull);           // 41,943,040 B  [65536][320]
    float* alphap = (float*)(ws + 110100480ull);        //  1,048,576 B -> total 111,149,056 B

    k0_prep<<<dim3(320,3,2), 128, 0, stream>>>(Wm,bm,Wihf,bihf,bhhf,Wihb,bihb,bhhb,W4bf,bc,bhhn);
    kW     <<<960,  256, 0, stream>>>(Wout,Wnode,Woutbf,Wnbf);
    kA     <<<1024, 256, 0, stream>>>(nodes,trip,Abf,Nbf);

    for (int h = 0; h < 2; ++h) {
        const u16* Ah   = (const u16*)Abf + (size_t)h*32768*128;
        u16*       Hidh = Hid + (size_t)h*32768*320;
        k1_gru<<<512, 256, 0, stream>>>(Ah, W4bf, bc, bhhn, Hhalf);
        k2_out<<<512, 256, 0, stream>>>(Hhalf, Woutbf, bout, Hidh);
    }

    k5_node<<<dim3(512,5), 256, 0, stream>>>((const u16*)Nbf,Wnbf,bnode,out + 38400);
    kC     <<<5120, 256, 0, stream>>>(ctx, Cbf);                // overlays Hhalf (dead)
    k3_attn<<<512,         256, 0, stream>>>((const u16*)Cbf, Hid, alphap);
    k4_rep <<<128,         640, 0, stream>>>(alphap,Hid,gamma,beta,out);
    hipMemsetAsync(out + 38400 + 9830400, 0, 32768*sizeof(float), stream);
}

// Round 11
// 388.956 us; speedup vs baseline: 1.1366x; 1.0368x over previous
//
#include <hip/hip_runtime.h>
#include <math.h>

#define D_NODE 100
#define D_HID  300
static const int TSEQ = 512, LQn = 256, NNODE = 256;

typedef unsigned int u32;
typedef unsigned short u16;
typedef __attribute__((ext_vector_type(8))) short bf16x8;   // 8 bf16 = 4 VGPRs
typedef __attribute__((ext_vector_type(4))) float f32x4;

__device__ __forceinline__ float bf2f(u16 v){ return __uint_as_float(((u32)v) << 16); }
__device__ __forceinline__ u16 f2bf(float f){
    u32 u = __float_as_uint(f);
    return (u16)((u + 0x7fffu + ((u >> 16) & 1u)) >> 16);
}
__device__ __forceinline__ u32 pack_bf(float lo, float hi){
    return ((u32)f2bf(lo)) | (((u32)f2bf(hi)) << 16);
}
__device__ __forceinline__ void gload_lds16(const void* g, void* l){
    __builtin_amdgcn_global_load_lds(
        (const __attribute__((address_space(1))) u32*)g,
        (__attribute__((address_space(3))) u32*)l, 16, 0, 0);
}
// fast sigmoid / tanh on v_exp_f32 + v_rcp_f32 (saturate correctly at +/-inf)
__device__ __forceinline__ float fsig(float x){
    return __builtin_amdgcn_rcpf(1.f + __expf(-x));
}
__device__ __forceinline__ float ftanh(float x){
    return 1.f - 2.f*__builtin_amdgcn_rcpf(1.f + __expf(2.f*x));
}

// ---------------- K_PREP: merged kW + kA + k0 (block-range partitioned, one launch).
// blocks [0,960)    : kW  — Wout -> [320][640] bf16, Wnode -> [320][128] bf16
// blocks [960,1984) : kA  — gather+mean -> Abf [65536][128]; nodes -> Nbf [32768][128] (wave/row)
// blocks [1984,3904): k0  — fold W_mean into GRU weights -> W4bf [dir][gate][320][128]
__global__ __launch_bounds__(256)
void k_prep(const float* __restrict__ Wout, const float* __restrict__ Wnode,
            u16* __restrict__ Woutbf, u16* __restrict__ Wnbf,
            const float* __restrict__ nodes, const int* __restrict__ trip,
            u32* __restrict__ Abf, u32* __restrict__ Nbf,
            const float* __restrict__ Wm, const float* __restrict__ bm,
            const float* __restrict__ Wihf, const float* __restrict__ bihf, const float* __restrict__ bhhf,
            const float* __restrict__ Wihb, const float* __restrict__ bihb, const float* __restrict__ bhhb,
            u16* __restrict__ W4bf, float* __restrict__ bc, float* __restrict__ bhhn)
{
    __shared__ float red[256];
    int bid = blockIdx.x;
    int tid = threadIdx.x;

    if (bid < 960) {
        // ---- kW ----
        int idx = bid*256 + tid;
        if (idx < 320*640) {
            int j = idx / 640, k = idx % 640;
            float v = 0.f;
            if (j < D_HID) {
                if (k < D_HID)                 v = Wout[(size_t)j*600 + k];
                else if (k >= 320 && k < 620)  v = Wout[(size_t)j*600 + (k - 20)];
            }
            Woutbf[idx] = f2bf(v);
        } else {
            int i2 = idx - 320*640;
            if (i2 < 320*128) {
                int j = i2 >> 7, k = i2 & 127;
                float v = (j < D_HID && k < D_NODE) ? Wnode[(size_t)j*D_NODE + k] : 0.f;
                Wnbf[i2] = f2bf(v);
            }
        }
    } else if (bid < 1984) {
        // ---- kA: one WAVE per row; lane l writes u32 col l (256 B coalesced store) ----
        int wid  = ((bid - 960)*256 + tid) >> 6;
        const int nw = (1024*256) >> 6;
        int lane = tid & 63;
        for (int r = wid; r < 98304; r += nw) {
            if (r < 65536) {
                int b = r >> 9;
                int h  = trip[(size_t)r*3];
                int t2 = trip[(size_t)r*3 + 2];
                const float* nh = nodes + ((size_t)b*NNODE + h)*D_NODE;
                const float* nt = nodes + ((size_t)b*NNODE + t2)*D_NODE;
                u32 v = 0;
                if (lane < 50) {
                    float2 a = *(const float2*)(nh + lane*2);
                    float2 c = *(const float2*)(nt + lane*2);
                    v = pack_bf(0.5f*(a.x + c.x), 0.5f*(a.y + c.y));
                }
                Abf[(size_t)r*64 + lane] = v;
            } else {
                int q = r - 65536;
                u32 v = 0;
                if (lane < 50) {
                    float2 a = *(const float2*)(nodes + (size_t)q*D_NODE + lane*2);
                    v = pack_bf(a.x, a.y);
                }
                Nbf[(size_t)q*64 + lane] = v;
            }
        }
    } else {
        // ---- k0 (adapted to 256 threads) ----
        int lin = bid - 1984;             // [0, 1920)
        int j   = lin % 320;
        int g   = (lin / 320) % 3;
        int dir = lin / 960;
        u16* wout = W4bf + ((size_t)((dir*3+g)*320 + j))*128;
        if (j >= D_HID) {
            if (tid < 128) wout[tid] = 0;
            if (tid == 0) { bc[(dir*3+g)*320 + j] = 0.f; if (g==2) bhhn[dir*320+j] = 0.f; }
            return;
        }
        const float* Wih = dir ? Wihb : Wihf;
        const float* bih = dir ? bihb : bihf;
        const float* bhh = dir ? bhhb : bhhf;
        const float* wrow = Wih + (size_t)(g*D_HID + j)*D_HID;
        if (tid < 128) {
            int k = tid;
            float s = 0.f;
            if (k < D_NODE)
                for (int q = 0; q < D_HID; ++q)
                    s = fmaf(wrow[q], Wm[q*D_NODE + k], s);
            wout[k] = f2bf(k < D_NODE ? s : 0.f);
        }
        float p = 0.f;
        for (int q = tid; q < D_HID; q += 256) p = fmaf(bm[q], wrow[q], p);
        red[tid] = p;
        __syncthreads();
        for (int off = 128; off > 0; off >>= 1) {
            if (tid < off) red[tid] += red[tid + off];
            __syncthreads();
        }
        if (tid == 0) {
            float base = bih[g*D_HID + j] + red[0];
            if (g < 2) base += bhh[g*D_HID + j];
            bc[(dir*3+g)*320 + j] = base;
            if (g == 2) bhhn[dir*320 + j] = bhh[2*D_HID + j];
        }
    }
}

// ---------------- KC: ctx -> bf16 padded [32768][320], uint4-vectorized ----------------
__global__ __launch_bounds__(256)
void kC(const float* __restrict__ ctx, u32* __restrict__ Cbf)
{
    int idx = blockIdx.x*256 + threadIdx.x;     // over 32768*40 uint4 groups
    int r = idx / 40, cp = idx % 40;
    int col = cp*8;
    uint4 v = {0,0,0,0};
    if (col < D_HID) {
        const float* base = ctx + (size_t)r*D_HID + col;
        float4 f0 = *(const float4*)base;
        v.x = pack_bf(f0.x, f0.y); v.y = pack_bf(f0.z, f0.w);
        if (col + 8 <= D_HID) {
            float4 f1 = *(const float4*)(base + 4);
            v.z = pack_bf(f1.x, f1.y); v.w = pack_bf(f1.z, f1.w);
        }
    }
    *(uint4*)(Cbf + (size_t)r*160 + cp*4) = v;
}

// ---------------- K1: GRU GEMM. One block = 64 rows x ALL 640 output cols (10 slices in-loop).
// A tile staged ONCE via global_load_lds -> registers (measured optimum: 47.8 us vs 50.2 direct-global,
// 72 us at 32 rows, 51 us dir-split). W fragments streamed from L2 per slice. ----------------
__global__ __launch_bounds__(256, 2)
void k1_gru(const u16* __restrict__ Abf, const u16* __restrict__ W4bf,
            const float* __restrict__ bc, const float* __restrict__ bhhn,
            u16* __restrict__ H)
{
    __shared__ __attribute__((aligned(16))) char smem[16384];
    int tid = threadIdx.x;
    int lane = tid & 63, w = tid >> 6;
    int l15 = lane & 15, lq = lane >> 4;
    int m0 = blockIdx.x * 64;

    // stage A tile [64][128] bf16 -> fragment-ordered LDS (tile = ms*4+ks)
    #pragma unroll
    for (int ks = 0; ks < 4; ++ks) {
        const u16* g = Abf + ((size_t)(m0 + w*16 + l15))*128 + ks*32 + lq*8;
        gload_lds16(g, smem + (size_t)((w*4 + ks)*64)*16);
    }
    __syncthreads();

    // A fragments to registers once — reused by all 10 slices
    bf16x8 af[4][4];
    #pragma unroll
    for (int ms = 0; ms < 4; ++ms)
        #pragma unroll
        for (int ks = 0; ks < 4; ++ks)
            af[ms][ks] = *(const bf16x8*)(smem + (size_t)(((ms*4+ks)*64 + lane))*16);

    #pragma unroll
    for (int st = 0; st < 10; ++st) {
        const int dir = (st < 5) ? 0 : 1;
        const int jg  = (st < 5) ? st : st - 5;
        const int j0w = jg*64 + w*16;
        const int j = j0w + l15;
        const u16* Wb = W4bf + (size_t)dir*3*320*128;

        bf16x8 bfr[3][4];
        #pragma unroll
        for (int g = 0; g < 3; ++g)
            #pragma unroll
            for (int ks = 0; ks < 4; ++ks)
                bfr[g][ks] = *(const bf16x8*)(Wb + ((size_t)(g*320 + j0w + l15))*128 + ks*32 + lq*8);

        f32x4 acc[4][3];
        #pragma unroll
        for (int ms = 0; ms < 4; ++ms)
            #pragma unroll
            for (int g = 0; g < 3; ++g)
                acc[ms][g] = (f32x4){0.f,0.f,0.f,0.f};

        #pragma unroll
        for (int ms = 0; ms < 4; ++ms)
            #pragma unroll
            for (int ks = 0; ks < 4; ++ks) {
                acc[ms][0] = __builtin_amdgcn_mfma_f32_16x16x32_bf16(af[ms][ks], bfr[0][ks], acc[ms][0], 0,0,0);
                acc[ms][1] = __builtin_amdgcn_mfma_f32_16x16x32_bf16(af[ms][ks], bfr[1][ks], acc[ms][1], 0,0,0);
                acc[ms][2] = __builtin_amdgcn_mfma_f32_16x16x32_bf16(af[ms][ks], bfr[2][ks], acc[ms][2], 0,0,0);
            }

        float bcr = bc[(dir*3+0)*320 + j];
        float bcz = bc[(dir*3+1)*320 + j];
        float bcn = bc[(dir*3+2)*320 + j];
        float bn2 = bhhn[dir*320 + j];
        bool ok = (j < D_HID);
        #pragma unroll
        for (int ms = 0; ms < 4; ++ms)
            #pragma unroll
            for (int i = 0; i < 4; ++i) {
                float r = fsig(acc[ms][0][i] + bcr);
                float z = fsig(acc[ms][1][i] + bcz);
                float n = ftanh(acc[ms][2][i] + bcn + r*bn2);
                float h = (1.f - z)*n;
                H[(size_t)(m0 + ms*16 + lq*4 + i)*640 + dir*320 + j] = ok ? f2bf(h) : (u16)0;
            }
    }
}

// ---------------- K2: Hid = tanh(H @ Wout^T + bout). One block = 64 rows x ALL 320 cols,
// K=640 streamed in 10 chunks of 64 through LDS (cross-wave tile sharing). H read exactly once. ----------------
__global__ __launch_bounds__(256, 2)
void k2_out(const u16* __restrict__ H, const u16* __restrict__ Woutbf,
            const float* __restrict__ bout, u16* __restrict__ Hid)
{
    __shared__ __attribute__((aligned(16))) char smem[8192];
    int tid = threadIdx.x;
    int lane = tid & 63, w = tid >> 6;      // w = j-quarter (80 cols each)
    int l15 = lane & 15, lq = lane >> 4;
    int m0 = blockIdx.x * 64;

    f32x4 acc[4][5];
    #pragma unroll
    for (int ms = 0; ms < 4; ++ms)
        #pragma unroll
        for (int jj = 0; jj < 5; ++jj)
            acc[ms][jj] = (f32x4){0.f,0.f,0.f,0.f};

    for (int c = 0; c < 10; ++c) {
        // stage chunk [64 rows][64 k] -> 8 fragment tiles (pm 0..3 x pk 0..1)
        #pragma unroll
        for (int r = 0; r < 2; ++r) {
            int p = w*2 + r, pm = p >> 1, pk = p & 1;
            gload_lds16(H + ((size_t)(m0 + pm*16 + l15))*640 + c*64 + pk*32 + lq*8,
                        smem + (size_t)(p*64)*16);
        }
        __syncthreads();
        #pragma unroll
        for (int pk = 0; pk < 2; ++pk) {
            bf16x8 bb[5];
            #pragma unroll
            for (int jj = 0; jj < 5; ++jj)
                bb[jj] = *(const bf16x8*)(Woutbf + ((size_t)(w*80 + jj*16 + l15))*640 + c*64 + pk*32 + lq*8);
            #pragma unroll
            for (int ms = 0; ms < 4; ++ms) {
                bf16x8 a = *(const bf16x8*)(smem + (size_t)(((ms*2+pk)*64 + lane))*16);
                #pragma unroll
                for (int jj = 0; jj < 5; ++jj)
                    acc[ms][jj] = __builtin_amdgcn_mfma_f32_16x16x32_bf16(a, bb[jj], acc[ms][jj], 0,0,0);
            }
        }
        __syncthreads();
    }

    #pragma unroll
    for (int jj = 0; jj < 5; ++jj) {
        int j = w*80 + jj*16 + l15;                 // < 320 always
        bool real = (j < D_HID);
        float bo = real ? bout[j] : 0.f;
        #pragma unroll
        for (int ms = 0; ms < 4; ++ms)
            #pragma unroll
            for (int i = 0; i < 4; ++i) {
                u16 v = real ? f2bf(ftanh(acc[ms][jj][i] + bo)) : (u16)0;
                Hid[(size_t)(m0 + ms*16 + lq*4 + i)*320 + j] = v;
            }
    }
}

// ---------------- K3: fused scores + softmax + partial-alpha.
// 1-D grid of 512, XCD-swizzled: all 4 m-blocks of a batch share id%8 -> same XCD L2. ----------------
__global__ __launch_bounds__(256, 2)
void k3_attn(const u16* __restrict__ Cbf, const u16* __restrict__ Hid,
             float* __restrict__ alphap)
{
    __shared__ char smemA[4096];       // 4 m-groups x 64 x 16 B
    __shared__ char smemB[32768];      // 32 t-groups x 64 x 16 B
    __shared__ float rmax[64*4], rsum[64*4];
    int tid = threadIdx.x;
    int lane = tid & 63, w = tid >> 6;
    int l15 = lane & 15, lq = lane >> 4;
    // id = xcd + 8*s ; s = bq*4 + mblk ; b = bq*8 + xcd
    int id = blockIdx.x;
    int xcd = id & 7, s = id >> 3;
    int bq = s >> 2, mblk = s & 3;
    int b = bq*8 + xcd;
    const u16* Ab = Cbf + ((size_t)b*LQn + mblk*64)*320;
    const u16* Bb = Hid + ((size_t)b*TSEQ)*320;

    f32x4 acc[4][8];
    #pragma unroll
    for (int ms = 0; ms < 4; ++ms)
        #pragma unroll
        for (int g = 0; g < 8; ++g)
            acc[ms][g] = (f32x4){0,0,0,0};

    for (int ks = 0; ks < 10; ++ks) {
        gload_lds16(Ab + ((size_t)(w*16 + l15))*320 + ks*32 + lq*8,
                    smemA + (size_t)(w*64)*16);
        #pragma unroll
        for (int i = 0; i < 8; ++i) {
            int nt = w*8 + i;
            gload_lds16(Bb + ((size_t)(nt*16 + l15))*320 + ks*32 + lq*8,
                        smemB + (size_t)(nt*64)*16);
        }
        __syncthreads();
        bf16x8 afr[4];
        #pragma unroll
        for (int ms = 0; ms < 4; ++ms)
            afr[ms] = *(const bf16x8*)(smemA + (size_t)((ms*64 + lane))*16);
        #pragma unroll
        for (int i = 0; i < 8; ++i) {
            bf16x8 bfr = *(const bf16x8*)(smemB + (size_t)(((w*8+i)*64 + lane))*16);
            #pragma unroll
            for (int ms = 0; ms < 4; ++ms)
                acc[ms][i] = __builtin_amdgcn_mfma_f32_16x16x32_bf16(afr[ms], bfr, acc[ms][i], 0,0,0);
        }
        __syncthreads();
    }

    #pragma unroll
    for (int ms = 0; ms < 4; ++ms)
        #pragma unroll
        for (int i = 0; i < 4; ++i) {
            float m = acc[ms][0][i];
            #pragma unroll
            for (int g = 1; g < 8; ++g) m = fmaxf(m, acc[ms][g][i]);
            m = fmaxf(m, __shfl_xor(m, 1));
            m = fmaxf(m, __shfl_xor(m, 2));
            m = fmaxf(m, __shfl_xor(m, 4));
            m = fmaxf(m, __shfl_xor(m, 8));
            if (l15 == 0) rmax[(ms*16 + lq*4 + i)*4 + w] = m;
        }
    __syncthreads();
    float mfin[4][4];
    #pragma unroll
    for (int ms = 0; ms < 4; ++ms)
        #pragma unroll
        for (int i = 0; i < 4; ++i) {
            float4 mv = *(const float4*)&rmax[(ms*16 + lq*4 + i)*4];
            mfin[ms][i] = fmaxf(fmaxf(mv.x, mv.y), fmaxf(mv.z, mv.w));
        }
    #pragma unroll
    for (int ms = 0; ms < 4; ++ms)
        #pragma unroll
        for (int i = 0; i < 4; ++i) {
            float s2 = 0.f;
            #pragma unroll
            for (int g = 0; g < 8; ++g) {
                float e = __expf(acc[ms][g][i] - mfin[ms][i]);
                acc[ms][g][i] = e;
                s2 += e;
            }
            s2 += __shfl_xor(s2, 1);
            s2 += __shfl_xor(s2, 2);
            s2 += __shfl_xor(s2, 4);
            s2 += __shfl_xor(s2, 8);
            if (l15 == 0) rsum[(ms*16 + lq*4 + i)*4 + w] = s2;
        }
    __syncthreads();
    float inv[4][4];
    #pragma unroll
    for (int ms = 0; ms < 4; ++ms)
        #pragma unroll
        for (int i = 0; i < 4; ++i) {
            float4 sv = *(const float4*)&rsum[(ms*16 + lq*4 + i)*4];
            inv[ms][i] = __builtin_amdgcn_rcpf(sv.x + sv.y + sv.z + sv.w);
        }
    float* ap = alphap + ((size_t)b*4 + mblk)*TSEQ;
    #pragma unroll
    for (int g = 0; g < 8; ++g) {
        float c = 0.f;
        #pragma unroll
        for (int ms = 0; ms < 4; ++ms)
            #pragma unroll
            for (int i = 0; i < 4; ++i)
                c = fmaf(acc[ms][g][i], inv[ms][i], c);
        c += __shfl_xor(c, 16);
        c += __shfl_xor(c, 32);
        if (lq == 0) ap[w*128 + g*16 + l15] = c;
    }
}

// ---------------- K4: rep = (sum of 4 partial alphas) @ Hid ; layernorm -> path_feature
// 640 threads, t-range split in two halves; dual accumulators halve the dep chain. ----------------
__global__ __launch_bounds__(640)
void k4_rep(const float* __restrict__ alphap, const u16* __restrict__ Hid,
            const float* __restrict__ gamma, const float* __restrict__ beta,
            float* __restrict__ outP)
{
    __shared__ float al[512];
    __shared__ float part[320];
    __shared__ float rs[10], rss[10];
    int tid = threadIdx.x, b = blockIdx.x;
    const float* ap = alphap + (size_t)b*4*TSEQ;
    for (int i = tid; i < 512; i += 640)
        al[i] = ap[i] + ap[512 + i] + ap[1024 + i] + ap[1536 + i];
    __syncthreads();
    int half = (tid >= 320) ? 1 : 0;
    int c = tid - half*320;
    float acc = 0.f;
    if (c < D_HID) {
        const u16* hp = Hid + (size_t)b*TSEQ*320 + (size_t)half*256*320 + c;
        float a0 = 0.f, a1 = 0.f;
        #pragma unroll 4
        for (int t = 0; t < 256; t += 2) {
            a0 = fmaf(al[half*256 + t],     bf2f(hp[(size_t)t*320]),       a0);
            a1 = fmaf(al[half*256 + t + 1], bf2f(hp[(size_t)(t+1)*320]),   a1);
        }
        acc = a0 + a1;
    }
    if (half) part[c] = acc;
    __syncthreads();
    float tot = 0.f;
    if (!half) tot = acc + part[c];
    float v = (!half && c < D_HID) ? tot : 0.f;
    float s = v, q = v*v;
    #pragma unroll
    for (int off = 32; off > 0; off >>= 1) { s += __shfl_xor(s, off, 64); q += __shfl_xor(q, off, 64); }
    if ((tid & 63) == 0) { rs[tid >> 6] = s; rss[tid >> 6] = q; }
    __syncthreads();
    float S = rs[0]+rs[1]+rs[2]+rs[3]+rs[4]+rs[5]+rs[6]+rs[7]+rs[8]+rs[9];
    float Q = rss[0]+rss[1]+rss[2]+rss[3]+rss[4]+rss[5]+rss[6]+rss[7]+rss[8]+rss[9];
    float mu = S * (1.f/300.f);
    float var = Q * (1.f/300.f) - mu*mu;
    if (!half && c < D_HID)
        outP[(size_t)b*D_HID + c] = (tot - mu) * rsqrtf(var + 1e-5f) * gamma[c] + beta[c];
}

// ---------------- K5: node_feature = nodes @ Wnode^T + bnode via MFMA (fp32 out) ----------------
__global__ __launch_bounds__(256)
void k5_node(const u16* __restrict__ Nbf, const u16* __restrict__ Wnbf,
             const float* __restrict__ bn, float* __restrict__ outN)
{
    __shared__ char smem[16384];
    int tid = threadIdx.x;
    int lane = tid & 63, w = tid >> 6;
    int l15 = lane & 15, lq = lane >> 4;
    int m0 = blockIdx.x * 64;
    int j0w = blockIdx.y*64 + w*16;

    bf16x8 bw[4];
    #pragma unroll
    for (int ks = 0; ks < 4; ++ks)
        bw[ks] = *(const bf16x8*)(Wnbf + ((size_t)(j0w + l15))*128 + ks*32 + lq*8);

    #pragma unroll
    for (int ks = 0; ks < 4; ++ks) {
        const u16* g = Nbf + ((size_t)(m0 + w*16 + l15))*128 + ks*32 + lq*8;
        gload_lds16(g, smem + (size_t)((w*4 + ks)*64)*16);
    }
    __syncthreads();

    f32x4 acc[4];
    #pragma unroll
    for (int ms = 0; ms < 4; ++ms) acc[ms] = (f32x4){0,0,0,0};
    #pragma unroll
    for (int ms = 0; ms < 4; ++ms)
        #pragma unroll
        for (int ks = 0; ks < 4; ++ks) {
            bf16x8 a = *(const bf16x8*)(smem + (size_t)(((ms*4+ks)*64 + lane))*16);
            acc[ms] = __builtin_amdgcn_mfma_f32_16x16x32_bf16(a, bw[ks], acc[ms], 0,0,0);
        }

    int j = j0w + l15;
    if (j < D_HID) {
        float bo = bn[j];
        #pragma unroll
        for (int ms = 0; ms < 4; ++ms)
            #pragma unroll
            for (int i = 0; i < 4; ++i)
                outN[(size_t)(m0 + ms*16 + lq*4 + i)*D_HID + j] = acc[ms][i] + bo;
    }
}

extern "C" void kernel_launch(void* const* d_in, const int* in_sizes, int n_in,
                              void* d_out, int out_size, void* d_ws, size_t ws_size,
                              hipStream_t stream) {
    const float* nodes  = (const float*)d_in[0];
    const float* ctx    = (const float*)d_in[1];
    const int*   trip   = (const int*)d_in[2];
    const float* Wm     = (const float*)d_in[4];
    const float* bm     = (const float*)d_in[5];
    const float* Wihf   = (const float*)d_in[6];
    const float* bihf   = (const float*)d_in[7];
    const float* bhhf   = (const float*)d_in[8];
    const float* Wihb   = (const float*)d_in[9];
    const float* bihb   = (const float*)d_in[10];
    const float* bhhb   = (const float*)d_in[11];
    const float* Wout   = (const float*)d_in[12];
    const float* bout   = (const float*)d_in[13];
    const float* Wnode  = (const float*)d_in[14];
    const float* bnode  = (const float*)d_in[15];
    const float* gamma  = (const float*)d_in[16];
    const float* beta   = (const float*)d_in[17];
    float* out = (float*)d_out;

    char* ws = (char*)d_ws;
    u16*   W4bf   = (u16*)(ws);                         //    491,520 B
    u16*   Woutbf = (u16*)(ws + 491520);                //    409,600 B  [320][640]
    u16*   Wnbf   = (u16*)(ws + 901120);                //     81,920 B
    float* bc     = (float*)(ws + 983040);              //      7,680 B
    float* bhhn   = (float*)(ws + 990720);              //      2,560 B
    u32*   Abf    = (u32*)(ws + 1048576);               // 16,777,216 B  [65536][64 u32]
    u32*   Nbf    = (u32*)(ws + 17825792ull);           //  8,388,608 B  [32768][64 u32]
    u16*   Hhalf  = (u16*)(ws + 26214400ull);           // 41,943,040 B  [32768][640] (per half)
    u32*   Cbf    = (u32*)(ws + 26214400ull);           // overlay on Hhalf (after 2nd k2): 20,971,520 B
    u16*   Hid    = (u16*)(ws + 68157440ull);           // 41,943,040 B  [65536][320]
    float* alphap = (float*)(ws + 110100480ull);        //  1,048,576 B -> total 111,149,056 B

    k_prep<<<3904, 256, 0, stream>>>(Wout, Wnode, Woutbf, Wnbf,
                                     nodes, trip, Abf, Nbf,
                                     Wm, bm, Wihf, bihf, bhhf, Wihb, bihb, bhhb,
                                     W4bf, bc, bhhn);

    for (int h = 0; h < 2; ++h) {
        const u16* Ah   = (const u16*)Abf + (size_t)h*32768*128;
        u16*       Hidh = Hid + (size_t)h*32768*320;
        k1_gru<<<512, 256, 0, stream>>>(Ah, W4bf, bc, bhhn, Hhalf);
        k2_out<<<512, 256, 0, stream>>>(Hhalf, Woutbf, bout, Hidh);
    }

    k5_node<<<dim3(512,5), 256, 0, stream>>>((const u16*)Nbf,Wnbf,bnode,out + 38400);
    kC     <<<5120, 256, 0, stream>>>(ctx, Cbf);                // overlays Hhalf (dead)
    k3_attn<<<512,         256, 0, stream>>>((const u16*)Cbf, Hid, alphap);
    k4_rep <<<128,         640, 0, stream>>>(alphap,Hid,gamma,beta,out);
    hipMemsetAsync(out + 38400 + 9830400, 0, 32768*sizeof(float), stream);
}